// Round 16
// baseline (493.884 us; speedup 1.0000x reference)
//
#include <hip/hip_runtime.h>

#define BATCH 512
#define NN    32
#define NVT   32
#define HS    501
#define VS    533
#define KP    512

typedef short bf16x8 __attribute__((ext_vector_type(8)));
typedef float f32x4  __attribute__((ext_vector_type(4)));
typedef unsigned long long u64;

__device__ __forceinline__ unsigned short f2bf(float f) {
    unsigned int u = __float_as_uint(f);
    u += 0x7fffu + ((u >> 16) & 1u);
    return (unsigned short)(u >> 16);
}
__device__ __forceinline__ float bf2f(unsigned short s) {
    return __uint_as_float(((unsigned int)s) << 16);
}
__device__ __forceinline__ float sigmoidf_(float x) { return 1.0f / (1.0f + __expf(-x)); }
__device__ __forceinline__ float tanhf_(float x)    { return 1.0f - 2.0f / (1.0f + __expf(2.0f * x)); }

// L2-hit cross-block fragment load: agent-scope relaxed atomic u64 pair -> sc0
// only (L1 bypass, L2 HIT). Relaxed => no inter-load ordering => stays pipelined.
// (volatile would emit sc0+sc1 = L2 bypass at IC latency, serialized.)
__device__ __forceinline__ bf16x8 ldfrag(const unsigned short* p) {
    union { u64 q[2]; bf16x8 v; } u;
    u64* a = (u64*)p;
    u.q[0] = __hip_atomic_load(a,     __ATOMIC_RELAXED, __HIP_MEMORY_SCOPE_AGENT);
    u.q[1] = __hip_atomic_load(a + 1, __ATOMIC_RELAXED, __HIP_MEMORY_SCOPE_AGENT);
    return u.v;
}

#define N_WHH  (3 * KP * KP)
#define N_WGM  (2 * KP * KP)
#define N_GI   (3 * NVT * KP)
#define N_IDW  (2 * NN * KP)
#define N_WRT  (KP * NN)
#define N_MSGB (BATCH * KP)
#define N_ADJC (BATCH * NN)
#define N_TOT  (N_WHH + N_WGM + N_GI + N_IDW + N_WRT + N_MSGB + N_ADJC)

// cb layout (u32): [0..7] claim counters; [16 .. 16+8*512) arrival flags
// (per XCD: 32 slots x 16-u32 stride); [16+4096 ..) release words (16-u32 stride).
#define CB_WORDS (16 + 8 * 512 + 8 * 16)

__global__ void prep_kernel(const float* __restrict__ W_hh, const float* __restrict__ Wg,
                            const float* __restrict__ Wm, const float* __restrict__ W_ih,
                            const float* __restrict__ b_ih, const float* __restrict__ b_hh,
                            const float* __restrict__ bg, const float* __restrict__ W_reg,
                            const float* __restrict__ adj,
                            unsigned short* __restrict__ Whh_p, unsigned short* __restrict__ Wgm_p,
                            float* __restrict__ gi_tab, float* __restrict__ idw,
                            float* __restrict__ WregT, unsigned short* __restrict__ MsgB,
                            unsigned int* __restrict__ adjcG)
{
    for (int i = blockIdx.x * blockDim.x + threadIdx.x; i < N_TOT; i += gridDim.x * blockDim.x) {
        int j = i;
        if (j < N_WHH) {
            int g = j >> 18, rem = j & (KP * KP - 1);
            int h = rem >> 9, k = rem & (KP - 1);
            float val = 0.0f;
            if (h < HS) {
                if (k < HS)        val = W_hh[(size_t)(g * HS + h) * HS + k];
                else if (k == HS)  val = b_hh[g * HS + h];   // bias folded at k=501
            }
            Whh_p[j] = f2bf(val);
            continue;
        }
        j -= N_WHH;
        if (j < N_WGM) {
            int m = j >> 18, rem = j & (KP * KP - 1);
            int h = rem >> 9, k = rem & (KP - 1);
            const float* src = m ? Wm : Wg;
            Wgm_p[j] = (h < HS && k < HS) ? f2bf(src[(size_t)h * VS + k]) : (unsigned short)0;
            continue;
        }
        j -= N_WGM;
        if (j < N_GI) {
            int g = j >> 14, typ = (j >> 9) & 31, h = j & (KP - 1);
            gi_tab[j] = (h < HS) ? (W_ih[(size_t)(g * HS + h) * NVT + typ] + b_ih[g * HS + h]) : 0.0f;
            continue;
        }
        j -= N_GI;
        if (j < N_IDW) {
            int m = j >> 14, v = (j >> 9) & 31, h = j & (KP - 1);
            float val = 0.0f;
            if (h < HS)
                val = m ? Wm[(size_t)h * VS + HS + v]
                        : (Wg[(size_t)h * VS + HS + v] + bg[h]);
            idw[j] = val;
            continue;
        }
        j -= N_IDW;
        if (j < N_WRT) {
            int k = j >> 5, ii = j & 31;
            WregT[j] = (k < HS) ? W_reg[(size_t)ii * HS + k] : 0.0f;
            continue;
        }
        j -= N_WRT;
        if (j < N_MSGB) {
            int k = j & (KP - 1);
            MsgB[j] = (k == HS) ? (unsigned short)0x3F80 : (unsigned short)0;  // bias col = 1.0
            continue;
        }
        j -= N_MSGB;
        {
            int b = j >> 5, vp = j & 31;
            unsigned int bits = 0;
            #pragma unroll
            for (int u = 0; u < 32; u++)
                bits |= (adj[((size_t)b * NN + u) * NN + vp] != 0.0f ? 1u : 0u) << u;
            adjcG[j] = bits;
        }
    }
}

// Contention-free slice barrier (32 blocks, one XCD): own-slot arrival store,
// wave-parallel master poll, single release word. (Verified r13/r14.)
__device__ __forceinline__ void sbar(unsigned int* flags, unsigned int* rel,
                                     int slot, unsigned int ph) {
    __syncthreads();
    const int t = threadIdx.x;
    if (t < 64) {
        if (t == 0)
            __hip_atomic_store(&flags[slot * 16], ph, __ATOMIC_RELAXED,
                               __HIP_MEMORY_SCOPE_AGENT);
        if (slot == 0) {
            unsigned long long notready;
            do {
                const unsigned int fv = (t < 32)
                    ? __hip_atomic_load(&flags[t * 16], __ATOMIC_RELAXED,
                                        __HIP_MEMORY_SCOPE_AGENT)
                    : ph;
                notready = __ballot(fv < ph);
                if (notready) __builtin_amdgcn_s_sleep(2);
            } while (notready);
            if (t == 0)
                __hip_atomic_store(rel, ph, __ATOMIC_RELAXED, __HIP_MEMORY_SCOPE_AGENT);
        } else if (t == 0) {
            while (__hip_atomic_load(rel, __ATOMIC_RELAXED, __HIP_MEMORY_SCOPE_AGENT) < ph)
                __builtin_amdgcn_s_sleep(2);
        }
    }
    __syncthreads();
}

// Persistent, XCD-local. 1024 threads (16 waves = 4/SIMD), split-K4.
// WLDS fragment-major (conflict-free weight reads, r14).
__global__ __launch_bounds__(1024, 4) void dvae_kernel(
    const unsigned short* __restrict__ Whh,   // [3*512][512] bf16 (k=501 = b_hh)
    const unsigned short* __restrict__ Wgm,   // [2*512][512] bf16
    const float* __restrict__ gi_tab,         // [3][32][512]
    const float* __restrict__ idw,            // [2][32][512]
    const int*   __restrict__ types,          // [512][32]
    const unsigned int* __restrict__ adjcG,   // [512][32] bitmask over u
    unsigned short* __restrict__ MsgB,        // [512][512] bf16 (+bias col 501)
    unsigned short* __restrict__ HvB,         // [512][512] bf16
    unsigned short* __restrict__ Ghist,       // [256 role][32 u][64 b][16 h] bf16
    float* __restrict__ HvF,                  // [512][512] f32 (final step)
    unsigned int* __restrict__ cb)            // claim + flags + release
{
    __shared__ unsigned short WLDS[5 * 8192];     // 80 KB fragment-major weights
    __shared__ float          Cred[3 * 12 * 256]; // 36 KB split-K reduce (kh=1..3)
    __shared__ float          MsgF_L[64 * 16];    // 4 KB f32 Msg mirror (own patch)
    __shared__ unsigned short GvL[64 * 16];       // 2 KB G_v staging
    __shared__ unsigned int   adjcL[64 * 32];     // 8 KB
    __shared__ int            slotS;

    // ---- self-assignment: slice == XCD ----
    int xcd;
    asm volatile("s_getreg_b32 %0, hwreg(HW_REG_XCC_ID)" : "=s"(xcd));
    xcd &= 7;
    if (threadIdx.x == 0)
        slotS = (int)__hip_atomic_fetch_add(&cb[xcd], 1u, __ATOMIC_RELAXED,
                                            __HIP_MEMORY_SCOPE_AGENT);
    __syncthreads();
    const int slot = slotS;
    if (slot >= 32) return;                      // surplus block
    const int hblk = slot, bslc = xcd;
    unsigned int* flags = cb + 16 + (bslc << 9);
    unsigned int* rel   = cb + 16 + 4096 + (bslc << 4);

    const int t    = threadIdx.x;
    const int lane = t & 63, w = t >> 6;          // 16 waves
    const int c16  = lane & 15, kg = lane >> 4;
    const int bt   = w & 3, kh = w >> 2;          // wave: batch-tile x K-quarter
    const int lofs = lane * 8;

    // ---- stage weights into LDS, fragment-major
    {
        const int kkf = t >> 6, l = t & 63;
        const int r16 = l & 15, k0 = (l >> 4) * 8 + kkf * 32;
        #pragma unroll
        for (int T = 0; T < 5; T++) {
            const unsigned short* src = (T < 3)
                ? Whh + (((size_t)(T * 512 + hblk * 16 + r16)) << 9) + k0
                : Wgm + (((size_t)((T - 3) * 512 + hblk * 16 + r16)) << 9) + k0;
            *(bf16x8*)&WLDS[T * 8192 + kkf * 512 + l * 8] = *(const bf16x8*)src;
        }
    }
    for (int i = t; i < 64 * 32; i += 1024) adjcL[i] = adjcG[bslc * (64 * 32) + i];
    for (int i = t; i < 64 * 16; i += 1024) MsgF_L[i] = 0.0f;
    __syncthreads();

    unsigned short* Gblk = Ghist + (size_t)(bslc * 32 + hblk) * (32 * 64 * 16);
    unsigned int ph = 0;

    for (int v = 0; v < NN; v++) {
        // ======== phase A: gh = Msg @ Whh^T (own 16 h, 64 rows, split-K4) ========
        f32x4 a0 = {0.f,0.f,0.f,0.f}, a1 = a0, a2 = a0;
        {
            const unsigned short* aptr =
                MsgB + (((size_t)(bslc * 64 + bt * 16 + c16)) << 9) + kh * 128 + kg * 8;
            bf16x8 af[4];
            #pragma unroll
            for (int kk = 0; kk < 4; kk++) af[kk] = ldfrag(aptr + kk * 32);
            #pragma unroll
            for (int kk = 0; kk < 4; kk++) {
                const int wo = (kh * 4 + kk) * 512 + lofs;
                a0 = __builtin_amdgcn_mfma_f32_16x16x32_bf16(af[kk], *(const bf16x8*)&WLDS[0 * 8192 + wo], a0, 0, 0, 0);
                a1 = __builtin_amdgcn_mfma_f32_16x16x32_bf16(af[kk], *(const bf16x8*)&WLDS[1 * 8192 + wo], a1, 0, 0, 0);
                a2 = __builtin_amdgcn_mfma_f32_16x16x32_bf16(af[kk], *(const bf16x8*)&WLDS[2 * 8192 + wo], a2, 0, 0, 0);
            }
        }
        if (kh > 0) {
            #pragma unroll
            for (int j = 0; j < 4; j++) {
                const int pi = (kg * 4 + j) * 16 + c16;
                Cred[((kh - 1) * 12 + bt * 3 + 0) * 256 + pi] = a0[j];
                Cred[((kh - 1) * 12 + bt * 3 + 1) * 256 + pi] = a1[j];
                Cred[((kh - 1) * 12 + bt * 3 + 2) * 256 + pi] = a2[j];
            }
        }
        __syncthreads();
        if (kh == 0) {
            const int h = hblk * 16 + c16;
            const bool ok = (h < HS);
            #pragma unroll
            for (int j = 0; j < 4; j++) {
                const int pi = (kg * 4 + j) * 16 + c16;
                const float s0 = a0[j] + Cred[(0 * 12 + bt * 3 + 0) * 256 + pi]
                                       + Cred[(1 * 12 + bt * 3 + 0) * 256 + pi]
                                       + Cred[(2 * 12 + bt * 3 + 0) * 256 + pi];
                const float s1 = a1[j] + Cred[(0 * 12 + bt * 3 + 1) * 256 + pi]
                                       + Cred[(1 * 12 + bt * 3 + 1) * 256 + pi]
                                       + Cred[(2 * 12 + bt * 3 + 1) * 256 + pi];
                const float s2 = a2[j] + Cred[(0 * 12 + bt * 3 + 2) * 256 + pi]
                                       + Cred[(1 * 12 + bt * 3 + 2) * 256 + pi]
                                       + Cred[(2 * 12 + bt * 3 + 2) * 256 + pi];
                const int bl = bt * 16 + kg * 4 + j;
                const int bg_ = bslc * 64 + bl;
                float hv = 0.0f;
                if (ok) {
                    const int typ = types[bg_ * 32 + v];
                    const float gr = gi_tab[(0 * 32 + typ) * 512 + h];
                    const float gz = gi_tab[(1 * 32 + typ) * 512 + h];
                    const float gn = gi_tab[(2 * 32 + typ) * 512 + h];
                    const float hmsg = MsgF_L[bl * 16 + c16];
                    const float r = sigmoidf_(gr + s0);
                    const float z = sigmoidf_(gz + s1);
                    const float n = tanhf_(gn + r * s2);
                    hv = (1.0f - z) * n + z * hmsg;
                }
                HvB[((size_t)bg_ << 9) + h] = f2bf(hv);
                if (v == NN - 1) HvF[((size_t)bg_ << 9) + h] = hv;
            }
        }
        if (v == NN - 1) break;
        sbar(flags, rel, hblk, ++ph);

        // ======== phase B: z = Hv @ {Wg,Wm}^T ========
        f32x4 b0 = {0.f,0.f,0.f,0.f}, b1 = b0;
        {
            const unsigned short* aptr =
                HvB + (((size_t)(bslc * 64 + bt * 16 + c16)) << 9) + kh * 128 + kg * 8;
            bf16x8 bfr[4];
            #pragma unroll
            for (int kk = 0; kk < 4; kk++) bfr[kk] = ldfrag(aptr + kk * 32);
            #pragma unroll
            for (int kk = 0; kk < 4; kk++) {
                const int wo = (kh * 4 + kk) * 512 + lofs;
                b0 = __builtin_amdgcn_mfma_f32_16x16x32_bf16(bfr[kk], *(const bf16x8*)&WLDS[3 * 8192 + wo], b0, 0, 0, 0);
                b1 = __builtin_amdgcn_mfma_f32_16x16x32_bf16(bfr[kk], *(const bf16x8*)&WLDS[4 * 8192 + wo], b1, 0, 0, 0);
            }
        }
        if (kh > 0) {
            #pragma unroll
            for (int j = 0; j < 4; j++) {
                const int pi = (kg * 4 + j) * 16 + c16;
                Cred[((kh - 1) * 12 + bt * 3 + 0) * 256 + pi] = b0[j];
                Cred[((kh - 1) * 12 + bt * 3 + 1) * 256 + pi] = b1[j];
            }
        }
        __syncthreads();
        if (kh == 0) {
            const int h = hblk * 16 + c16;
            const bool ok = (h < HS);
            #pragma unroll
            for (int j = 0; j < 4; j++) {
                const int pi = (kg * 4 + j) * 16 + c16;
                const float s0 = b0[j] + Cred[(0 * 12 + bt * 3 + 0) * 256 + pi]
                                       + Cred[(1 * 12 + bt * 3 + 0) * 256 + pi]
                                       + Cred[(2 * 12 + bt * 3 + 0) * 256 + pi];
                const float s1 = b1[j] + Cred[(0 * 12 + bt * 3 + 1) * 256 + pi]
                                       + Cred[(1 * 12 + bt * 3 + 1) * 256 + pi]
                                       + Cred[(2 * 12 + bt * 3 + 1) * 256 + pi];
                const int bl = bt * 16 + kg * 4 + j;
                float gq = 0.0f;
                if (ok) {
                    const float zg = s0 + idw[(0 * 32 + v) * 512 + h];
                    const float zm = s1 + idw[(1 * 32 + v) * 512 + h];
                    gq = sigmoidf_(zg) * zm;
                }
                GvL[bl * 16 + c16] = f2bf(gq);
            }
        }
        __syncthreads();
        // ---- gather: persist G_v (block-private), assemble Msg_{v+1} own patch
        if (t < 128) {
            const int bl = t >> 1, h8 = (t & 1) * 8;
            const bf16x8 g = *(const bf16x8*)&GvL[bl * 16 + h8];
            *(bf16x8*)&Gblk[((size_t)v * 64 + bl) * 16 + h8] = g;

            float msg[8] = {0.f,0.f,0.f,0.f,0.f,0.f,0.f,0.f};
            unsigned int mask = adjcL[bl * 32 + (v + 1)] & ((2u << v) - 1u);   // u <= v
            if ((mask >> v) & 1u) {
                #pragma unroll
                for (int x = 0; x < 8; x++) msg[x] += bf2f((unsigned short)g[x]);
                mask &= ~(1u << v);
            }
            while (mask) {
                const int u = __builtin_ctz(mask); mask &= mask - 1u;
                const bf16x8 a = *(const bf16x8*)&Gblk[((size_t)u * 64 + bl) * 16 + h8];
                #pragma unroll
                for (int x = 0; x < 8; x++) msg[x] += bf2f((unsigned short)a[x]);
            }
            const int hb_ = hblk * 16 + h8;
            if (hb_ <= HS && HS < hb_ + 8) msg[HS - hb_] = 1.0f;   // bias col k=501
            bf16x8 mb;
            #pragma unroll
            for (int x = 0; x < 8; x++) mb[x] = (short)f2bf(msg[x]);
            *(bf16x8*)&MsgB[(((size_t)(bslc * 64 + bl)) << 9) + hb_] = mb;
            #pragma unroll
            for (int x = 0; x < 8; x++) MsgF_L[bl * 16 + h8 + x] = msg[x];
        }
        sbar(flags, rel, hblk, ++ph);
    }
}

// mu = Hv31 @ W_reg^T + b_reg
__global__ __launch_bounds__(256) void final_kernel(
    const float* __restrict__ HvF,       // [512][512]
    const float* __restrict__ WregT,     // [512][32]
    const float* __restrict__ b_reg,     // [32]
    float* __restrict__ out)             // [512][32]
{
    const int t = blockIdx.x * 256 + threadIdx.x;
    const int b = t >> 5, i = t & 31;
    float s = b_reg[i];
    const float* hp = HvF + ((size_t)b << 9);
    #pragma unroll 4
    for (int k = 0; k < KP; k++) s += hp[k] * WregT[k * 32 + i];
    out[b * 32 + i] = s;
}

extern "C" void kernel_launch(void* const* d_in, const int* in_sizes, int n_in,
                              void* d_out, int out_size, void* d_ws, size_t ws_size,
                              hipStream_t stream) {
    const int*   node_types = (const int*)  d_in[0];
    const float* adj        = (const float*)d_in[1];
    const float* Wg         = (const float*)d_in[2];
    const float* bg         = (const float*)d_in[3];
    const float* Wm         = (const float*)d_in[4];
    const float* W_ih       = (const float*)d_in[5];
    const float* b_ih       = (const float*)d_in[6];
    const float* W_hh       = (const float*)d_in[7];
    const float* b_hh       = (const float*)d_in[8];
    const float* W_reg      = (const float*)d_in[9];
    const float* b_reg      = (const float*)d_in[10];
    float* out = (float*)d_out;

    char* p = (char*)d_ws;
    unsigned short* Whh_p = (unsigned short*)p; p += (size_t)N_WHH * 2;
    unsigned short* Wgm_p = (unsigned short*)p; p += (size_t)N_WGM * 2;
    float* gi_tab = (float*)p; p += (size_t)N_GI * 4;
    float* idw    = (float*)p; p += (size_t)N_IDW * 4;
    float* WregT  = (float*)p; p += (size_t)N_WRT * 4;
    float* HvF    = (float*)p; p += (size_t)BATCH * KP * 4;
    unsigned short* MsgB = (unsigned short*)p; p += (size_t)N_MSGB * 2;
    unsigned short* HvB  = (unsigned short*)p; p += (size_t)BATCH * KP * 2;
    unsigned int* adjcG  = (unsigned int*)p;  p += (size_t)N_ADJC * 4;
    unsigned int* cb     = (unsigned int*)p;  p += (size_t)CB_WORDS * 4;
    unsigned short* Ghist = (unsigned short*)p; p += (size_t)256 * 32 * 64 * 16 * 2;

    hipMemsetAsync(cb, 0, CB_WORDS * 4, stream);
    prep_kernel<<<1024, 256, 0, stream>>>(W_hh, Wg, Wm, W_ih, b_ih, b_hh, bg, W_reg, adj,
                                          Whh_p, Wgm_p, gi_tab, idw, WregT, MsgB, adjcG);
    dvae_kernel<<<1024, 1024, 0, stream>>>(Whh_p, Wgm_p, gi_tab, idw, node_types, adjcG,
                                           MsgB, HvB, Ghist, HvF, cb);
    final_kernel<<<(BATCH * NN) / 256, 256, 0, stream>>>(HvF, WregT, b_reg, out);
}

// Round 17
// 404.610 us; speedup vs baseline: 1.2206x; 1.2206x over previous
//
#include <hip/hip_runtime.h>

#define BATCH 512
#define NN    32
#define NVT   32
#define HS    501
#define VS    533
#define KP    512

typedef short bf16x8 __attribute__((ext_vector_type(8)));
typedef float f32x4  __attribute__((ext_vector_type(4)));

__device__ __forceinline__ unsigned short f2bf(float f) {
    unsigned int u = __float_as_uint(f);
    u += 0x7fffu + ((u >> 16) & 1u);
    return (unsigned short)(u >> 16);
}
__device__ __forceinline__ float bf2f(unsigned short s) {
    return __uint_as_float(((unsigned int)s) << 16);
}
__device__ __forceinline__ float sigmoidf_(float x) { return 1.0f / (1.0f + __expf(-x)); }
__device__ __forceinline__ float tanhf_(float x)    { return 1.0f - 2.0f / (1.0f + __expf(2.0f * x)); }

// 4 pipelined L1-bypass / XCD-L2-HIT loads: sc0 only. Producer and consumer are
// on the SAME XCD by construction, so the shared L2 holds the fresh data; sc0
// bypasses the (possibly stale) L1. Single vmcnt(0) keeps all 4 in flight.
__device__ __forceinline__ void load4_sc0(const unsigned short* p,
                                          bf16x8& r0, bf16x8& r1,
                                          bf16x8& r2, bf16x8& r3) {
    asm volatile(
        "global_load_dwordx4 %0, %4, off sc0\n\t"
        "global_load_dwordx4 %1, %4, off offset:64 sc0\n\t"
        "global_load_dwordx4 %2, %4, off offset:128 sc0\n\t"
        "global_load_dwordx4 %3, %4, off offset:192 sc0\n\t"
        "s_waitcnt vmcnt(0)"
        : "=&v"(r0), "=&v"(r1), "=&v"(r2), "=&v"(r3)
        : "v"(p)
        : "memory");
}

#define N_WHH  (3 * KP * KP)
#define N_WGM  (2 * KP * KP)
#define N_GI   (3 * NVT * KP)
#define N_IDW  (2 * NN * KP)
#define N_WRT  (KP * NN)
#define N_MSGB (BATCH * KP)
#define N_ADJC (BATCH * NN)
#define N_TOT  (N_WHH + N_WGM + N_GI + N_IDW + N_WRT + N_MSGB + N_ADJC)

// cb layout (u32): [0..7] claim counters; [16 .. 16+8*512) arrival flags
// (per XCD: 32 slots x 16-u32 stride); [16+4096 ..) release words (16-u32 stride).
#define CB_WORDS (16 + 8 * 512 + 8 * 16)

__global__ void prep_kernel(const float* __restrict__ W_hh, const float* __restrict__ Wg,
                            const float* __restrict__ Wm, const float* __restrict__ W_ih,
                            const float* __restrict__ b_ih, const float* __restrict__ b_hh,
                            const float* __restrict__ bg, const float* __restrict__ W_reg,
                            const float* __restrict__ adj,
                            unsigned short* __restrict__ Whh_p, unsigned short* __restrict__ Wgm_p,
                            float* __restrict__ gi_tab, float* __restrict__ idw,
                            float* __restrict__ WregT, unsigned short* __restrict__ MsgB,
                            unsigned int* __restrict__ adjcG)
{
    for (int i = blockIdx.x * blockDim.x + threadIdx.x; i < N_TOT; i += gridDim.x * blockDim.x) {
        int j = i;
        if (j < N_WHH) {
            int g = j >> 18, rem = j & (KP * KP - 1);
            int h = rem >> 9, k = rem & (KP - 1);
            float val = 0.0f;
            if (h < HS) {
                if (k < HS)        val = W_hh[(size_t)(g * HS + h) * HS + k];
                else if (k == HS)  val = b_hh[g * HS + h];   // bias folded at k=501
            }
            Whh_p[j] = f2bf(val);
            continue;
        }
        j -= N_WHH;
        if (j < N_WGM) {
            int m = j >> 18, rem = j & (KP * KP - 1);
            int h = rem >> 9, k = rem & (KP - 1);
            const float* src = m ? Wm : Wg;
            Wgm_p[j] = (h < HS && k < HS) ? f2bf(src[(size_t)h * VS + k]) : (unsigned short)0;
            continue;
        }
        j -= N_WGM;
        if (j < N_GI) {
            int g = j >> 14, typ = (j >> 9) & 31, h = j & (KP - 1);
            gi_tab[j] = (h < HS) ? (W_ih[(size_t)(g * HS + h) * NVT + typ] + b_ih[g * HS + h]) : 0.0f;
            continue;
        }
        j -= N_GI;
        if (j < N_IDW) {
            int m = j >> 14, v = (j >> 9) & 31, h = j & (KP - 1);
            float val = 0.0f;
            if (h < HS)
                val = m ? Wm[(size_t)h * VS + HS + v]
                        : (Wg[(size_t)h * VS + HS + v] + bg[h]);
            idw[j] = val;
            continue;
        }
        j -= N_IDW;
        if (j < N_WRT) {
            int k = j >> 5, ii = j & 31;
            WregT[j] = (k < HS) ? W_reg[(size_t)ii * HS + k] : 0.0f;
            continue;
        }
        j -= N_WRT;
        if (j < N_MSGB) {
            int k = j & (KP - 1);
            MsgB[j] = (k == HS) ? (unsigned short)0x3F80 : (unsigned short)0;  // bias col = 1.0
            continue;
        }
        j -= N_MSGB;
        {
            int b = j >> 5, vp = j & 31;
            unsigned int bits = 0;
            #pragma unroll
            for (int u = 0; u < 32; u++)
                bits |= (adj[((size_t)b * NN + u) * NN + vp] != 0.0f ? 1u : 0u) << u;
            adjcG[j] = bits;
        }
    }
}

// Contention-free slice barrier (32 blocks, one XCD): own-slot arrival store,
// wave-parallel master poll, single release word. (Verified r13/r14/r16.)
__device__ __forceinline__ void sbar(unsigned int* flags, unsigned int* rel,
                                     int slot, unsigned int ph) {
    __syncthreads();
    const int t = threadIdx.x;
    if (t < 64) {
        if (t == 0)
            __hip_atomic_store(&flags[slot * 16], ph, __ATOMIC_RELAXED,
                               __HIP_MEMORY_SCOPE_AGENT);
        if (slot == 0) {
            unsigned long long notready;
            do {
                const unsigned int fv = (t < 32)
                    ? __hip_atomic_load(&flags[t * 16], __ATOMIC_RELAXED,
                                        __HIP_MEMORY_SCOPE_AGENT)
                    : ph;
                notready = __ballot(fv < ph);
                if (notready) __builtin_amdgcn_s_sleep(2);
            } while (notready);
            if (t == 0)
                __hip_atomic_store(rel, ph, __ATOMIC_RELAXED, __HIP_MEMORY_SCOPE_AGENT);
        } else if (t == 0) {
            while (__hip_atomic_load(rel, __ATOMIC_RELAXED, __HIP_MEMORY_SCOPE_AGENT) < ph)
                __builtin_amdgcn_s_sleep(2);
        }
    }
    __syncthreads();
}

// Persistent, XCD-local. 1024 threads (16 waves = 4/SIMD), split-K4.
// WLDS fragment-major (conflict-free weight reads, r14).
__global__ __launch_bounds__(1024, 4) void dvae_kernel(
    const unsigned short* __restrict__ Whh,   // [3*512][512] bf16 (k=501 = b_hh)
    const unsigned short* __restrict__ Wgm,   // [2*512][512] bf16
    const float* __restrict__ gi_tab,         // [3][32][512]
    const float* __restrict__ idw,            // [2][32][512]
    const int*   __restrict__ types,          // [512][32]
    const unsigned int* __restrict__ adjcG,   // [512][32] bitmask over u
    unsigned short* __restrict__ MsgB,        // [512][512] bf16 (+bias col 501)
    unsigned short* __restrict__ HvB,         // [512][512] bf16
    unsigned short* __restrict__ Ghist,       // [256 role][32 u][64 b][16 h] bf16
    float* __restrict__ HvF,                  // [512][512] f32 (final step)
    unsigned int* __restrict__ cb)            // claim + flags + release
{
    __shared__ unsigned short WLDS[5 * 8192];     // 80 KB fragment-major weights
    __shared__ float          Cred[3 * 12 * 256]; // 36 KB split-K reduce (kh=1..3)
    __shared__ float          MsgF_L[64 * 16];    // 4 KB f32 Msg mirror (own patch)
    __shared__ unsigned short GvL[64 * 16];       // 2 KB G_v staging
    __shared__ unsigned int   adjcL[64 * 32];     // 8 KB
    __shared__ int            slotS;

    // ---- self-assignment: slice == XCD ----
    int xcd;
    asm volatile("s_getreg_b32 %0, hwreg(HW_REG_XCC_ID)" : "=s"(xcd));
    xcd &= 7;
    if (threadIdx.x == 0)
        slotS = (int)__hip_atomic_fetch_add(&cb[xcd], 1u, __ATOMIC_RELAXED,
                                            __HIP_MEMORY_SCOPE_AGENT);
    __syncthreads();
    const int slot = slotS;
    if (slot >= 32) return;                      // surplus block
    const int hblk = slot, bslc = xcd;
    unsigned int* flags = cb + 16 + (bslc << 9);
    unsigned int* rel   = cb + 16 + 4096 + (bslc << 4);

    const int t    = threadIdx.x;
    const int lane = t & 63, w = t >> 6;          // 16 waves
    const int c16  = lane & 15, kg = lane >> 4;
    const int bt   = w & 3, kh = w >> 2;          // wave: batch-tile x K-quarter
    const int lofs = lane * 8;

    // ---- stage weights into LDS, fragment-major
    {
        const int kkf = t >> 6, l = t & 63;
        const int r16 = l & 15, k0 = (l >> 4) * 8 + kkf * 32;
        #pragma unroll
        for (int T = 0; T < 5; T++) {
            const unsigned short* src = (T < 3)
                ? Whh + (((size_t)(T * 512 + hblk * 16 + r16)) << 9) + k0
                : Wgm + (((size_t)((T - 3) * 512 + hblk * 16 + r16)) << 9) + k0;
            *(bf16x8*)&WLDS[T * 8192 + kkf * 512 + l * 8] = *(const bf16x8*)src;
        }
    }
    for (int i = t; i < 64 * 32; i += 1024) adjcL[i] = adjcG[bslc * (64 * 32) + i];
    for (int i = t; i < 64 * 16; i += 1024) MsgF_L[i] = 0.0f;
    __syncthreads();

    unsigned short* Gblk = Ghist + (size_t)(bslc * 32 + hblk) * (32 * 64 * 16);
    unsigned int ph = 0;

    for (int v = 0; v < NN; v++) {
        // ======== phase A: gh = Msg @ Whh^T (own 16 h, 64 rows, split-K4) ========
        f32x4 a0 = {0.f,0.f,0.f,0.f}, a1 = a0, a2 = a0;
        {
            const unsigned short* aptr =
                MsgB + (((size_t)(bslc * 64 + bt * 16 + c16)) << 9) + kh * 128 + kg * 8;
            bf16x8 af[4];
            load4_sc0(aptr, af[0], af[1], af[2], af[3]);
            #pragma unroll
            for (int kk = 0; kk < 4; kk++) {
                const int wo = (kh * 4 + kk) * 512 + lofs;
                a0 = __builtin_amdgcn_mfma_f32_16x16x32_bf16(af[kk], *(const bf16x8*)&WLDS[0 * 8192 + wo], a0, 0, 0, 0);
                a1 = __builtin_amdgcn_mfma_f32_16x16x32_bf16(af[kk], *(const bf16x8*)&WLDS[1 * 8192 + wo], a1, 0, 0, 0);
                a2 = __builtin_amdgcn_mfma_f32_16x16x32_bf16(af[kk], *(const bf16x8*)&WLDS[2 * 8192 + wo], a2, 0, 0, 0);
            }
        }
        if (kh > 0) {
            #pragma unroll
            for (int j = 0; j < 4; j++) {
                const int pi = (kg * 4 + j) * 16 + c16;
                Cred[((kh - 1) * 12 + bt * 3 + 0) * 256 + pi] = a0[j];
                Cred[((kh - 1) * 12 + bt * 3 + 1) * 256 + pi] = a1[j];
                Cred[((kh - 1) * 12 + bt * 3 + 2) * 256 + pi] = a2[j];
            }
        }
        __syncthreads();
        if (kh == 0) {
            const int h = hblk * 16 + c16;
            const bool ok = (h < HS);
            #pragma unroll
            for (int j = 0; j < 4; j++) {
                const int pi = (kg * 4 + j) * 16 + c16;
                const float s0 = a0[j] + Cred[(0 * 12 + bt * 3 + 0) * 256 + pi]
                                       + Cred[(1 * 12 + bt * 3 + 0) * 256 + pi]
                                       + Cred[(2 * 12 + bt * 3 + 0) * 256 + pi];
                const float s1 = a1[j] + Cred[(0 * 12 + bt * 3 + 1) * 256 + pi]
                                       + Cred[(1 * 12 + bt * 3 + 1) * 256 + pi]
                                       + Cred[(2 * 12 + bt * 3 + 1) * 256 + pi];
                const float s2 = a2[j] + Cred[(0 * 12 + bt * 3 + 2) * 256 + pi]
                                       + Cred[(1 * 12 + bt * 3 + 2) * 256 + pi]
                                       + Cred[(2 * 12 + bt * 3 + 2) * 256 + pi];
                const int bl = bt * 16 + kg * 4 + j;
                const int bg_ = bslc * 64 + bl;
                float hv = 0.0f;
                if (ok) {
                    const int typ = types[bg_ * 32 + v];
                    const float gr = gi_tab[(0 * 32 + typ) * 512 + h];
                    const float gz = gi_tab[(1 * 32 + typ) * 512 + h];
                    const float gn = gi_tab[(2 * 32 + typ) * 512 + h];
                    const float hmsg = MsgF_L[bl * 16 + c16];
                    const float r = sigmoidf_(gr + s0);
                    const float z = sigmoidf_(gz + s1);
                    const float n = tanhf_(gn + r * s2);
                    hv = (1.0f - z) * n + z * hmsg;
                }
                HvB[((size_t)bg_ << 9) + h] = f2bf(hv);
                if (v == NN - 1) HvF[((size_t)bg_ << 9) + h] = hv;
            }
        }
        if (v == NN - 1) break;
        sbar(flags, rel, hblk, ++ph);

        // ======== phase B: z = Hv @ {Wg,Wm}^T ========
        f32x4 b0 = {0.f,0.f,0.f,0.f}, b1 = b0;
        {
            const unsigned short* aptr =
                HvB + (((size_t)(bslc * 64 + bt * 16 + c16)) << 9) + kh * 128 + kg * 8;
            bf16x8 bfr[4];
            load4_sc0(aptr, bfr[0], bfr[1], bfr[2], bfr[3]);
            #pragma unroll
            for (int kk = 0; kk < 4; kk++) {
                const int wo = (kh * 4 + kk) * 512 + lofs;
                b0 = __builtin_amdgcn_mfma_f32_16x16x32_bf16(bfr[kk], *(const bf16x8*)&WLDS[3 * 8192 + wo], b0, 0, 0, 0);
                b1 = __builtin_amdgcn_mfma_f32_16x16x32_bf16(bfr[kk], *(const bf16x8*)&WLDS[4 * 8192 + wo], b1, 0, 0, 0);
            }
        }
        if (kh > 0) {
            #pragma unroll
            for (int j = 0; j < 4; j++) {
                const int pi = (kg * 4 + j) * 16 + c16;
                Cred[((kh - 1) * 12 + bt * 3 + 0) * 256 + pi] = b0[j];
                Cred[((kh - 1) * 12 + bt * 3 + 1) * 256 + pi] = b1[j];
            }
        }
        __syncthreads();
        if (kh == 0) {
            const int h = hblk * 16 + c16;
            const bool ok = (h < HS);
            #pragma unroll
            for (int j = 0; j < 4; j++) {
                const int pi = (kg * 4 + j) * 16 + c16;
                const float s0 = b0[j] + Cred[(0 * 12 + bt * 3 + 0) * 256 + pi]
                                       + Cred[(1 * 12 + bt * 3 + 0) * 256 + pi]
                                       + Cred[(2 * 12 + bt * 3 + 0) * 256 + pi];
                const float s1 = b1[j] + Cred[(0 * 12 + bt * 3 + 1) * 256 + pi]
                                       + Cred[(1 * 12 + bt * 3 + 1) * 256 + pi]
                                       + Cred[(2 * 12 + bt * 3 + 1) * 256 + pi];
                const int bl = bt * 16 + kg * 4 + j;
                float gq = 0.0f;
                if (ok) {
                    const float zg = s0 + idw[(0 * 32 + v) * 512 + h];
                    const float zm = s1 + idw[(1 * 32 + v) * 512 + h];
                    gq = sigmoidf_(zg) * zm;
                }
                GvL[bl * 16 + c16] = f2bf(gq);
            }
        }
        __syncthreads();
        // ---- gather: persist G_v (block-private), assemble Msg_{v+1} own patch
        if (t < 128) {
            const int bl = t >> 1, h8 = (t & 1) * 8;
            const bf16x8 g = *(const bf16x8*)&GvL[bl * 16 + h8];
            *(bf16x8*)&Gblk[((size_t)v * 64 + bl) * 16 + h8] = g;

            float msg[8] = {0.f,0.f,0.f,0.f,0.f,0.f,0.f,0.f};
            unsigned int mask = adjcL[bl * 32 + (v + 1)] & ((2u << v) - 1u);   // u <= v
            if ((mask >> v) & 1u) {
                #pragma unroll
                for (int x = 0; x < 8; x++) msg[x] += bf2f((unsigned short)g[x]);
                mask &= ~(1u << v);
            }
            while (mask) {
                const int u = __builtin_ctz(mask); mask &= mask - 1u;
                const bf16x8 a = *(const bf16x8*)&Gblk[((size_t)u * 64 + bl) * 16 + h8];
                #pragma unroll
                for (int x = 0; x < 8; x++) msg[x] += bf2f((unsigned short)a[x]);
            }
            const int hb_ = hblk * 16 + h8;
            if (hb_ <= HS && HS < hb_ + 8) msg[HS - hb_] = 1.0f;   // bias col k=501
            bf16x8 mb;
            #pragma unroll
            for (int x = 0; x < 8; x++) mb[x] = (short)f2bf(msg[x]);
            *(bf16x8*)&MsgB[(((size_t)(bslc * 64 + bl)) << 9) + hb_] = mb;
            #pragma unroll
            for (int x = 0; x < 8; x++) MsgF_L[bl * 16 + h8 + x] = msg[x];
        }
        sbar(flags, rel, hblk, ++ph);
    }
}

// mu = Hv31 @ W_reg^T + b_reg
__global__ __launch_bounds__(256) void final_kernel(
    const float* __restrict__ HvF,       // [512][512]
    const float* __restrict__ WregT,     // [512][32]
    const float* __restrict__ b_reg,     // [32]
    float* __restrict__ out)             // [512][32]
{
    const int t = blockIdx.x * 256 + threadIdx.x;
    const int b = t >> 5, i = t & 31;
    float s = b_reg[i];
    const float* hp = HvF + ((size_t)b << 9);
    #pragma unroll 4
    for (int k = 0; k < KP; k++) s += hp[k] * WregT[k * 32 + i];
    out[b * 32 + i] = s;
}

extern "C" void kernel_launch(void* const* d_in, const int* in_sizes, int n_in,
                              void* d_out, int out_size, void* d_ws, size_t ws_size,
                              hipStream_t stream) {
    const int*   node_types = (const int*)  d_in[0];
    const float* adj        = (const float*)d_in[1];
    const float* Wg         = (const float*)d_in[2];
    const float* bg         = (const float*)d_in[3];
    const float* Wm         = (const float*)d_in[4];
    const float* W_ih       = (const float*)d_in[5];
    const float* b_ih       = (const float*)d_in[6];
    const float* W_hh       = (const float*)d_in[7];
    const float* b_hh       = (const float*)d_in[8];
    const float* W_reg      = (const float*)d_in[9];
    const float* b_reg      = (const float*)d_in[10];
    float* out = (float*)d_out;

    char* p = (char*)d_ws;
    unsigned short* Whh_p = (unsigned short*)p; p += (size_t)N_WHH * 2;
    unsigned short* Wgm_p = (unsigned short*)p; p += (size_t)N_WGM * 2;
    float* gi_tab = (float*)p; p += (size_t)N_GI * 4;
    float* idw    = (float*)p; p += (size_t)N_IDW * 4;
    float* WregT  = (float*)p; p += (size_t)N_WRT * 4;
    float* HvF    = (float*)p; p += (size_t)BATCH * KP * 4;
    unsigned short* MsgB = (unsigned short*)p; p += (size_t)N_MSGB * 2;
    unsigned short* HvB  = (unsigned short*)p; p += (size_t)BATCH * KP * 2;
    unsigned int* adjcG  = (unsigned int*)p;  p += (size_t)N_ADJC * 4;
    unsigned int* cb     = (unsigned int*)p;  p += (size_t)CB_WORDS * 4;
    unsigned short* Ghist = (unsigned short*)p; p += (size_t)256 * 32 * 64 * 16 * 2;

    hipMemsetAsync(cb, 0, CB_WORDS * 4, stream);
    prep_kernel<<<1024, 256, 0, stream>>>(W_hh, Wg, Wm, W_ih, b_ih, b_hh, bg, W_reg, adj,
                                          Whh_p, Wgm_p, gi_tab, idw, WregT, MsgB, adjcG);
    dvae_kernel<<<1024, 1024, 0, stream>>>(Whh_p, Wgm_p, gi_tab, idw, node_types, adjcG,
                                           MsgB, HvB, Ghist, HvF, cb);
    final_kernel<<<(BATCH * NN) / 256, 256, 0, stream>>>(HvF, WregT, b_reg, out);
}

// Round 18
// 395.093 us; speedup vs baseline: 1.2500x; 1.0241x over previous
//
#include <hip/hip_runtime.h>

#define BATCH 512
#define NN    32
#define NVT   32
#define HS    501
#define VS    533
#define KP    512

typedef short bf16x8 __attribute__((ext_vector_type(8)));
typedef float f32x4  __attribute__((ext_vector_type(4)));

__device__ __forceinline__ unsigned short f2bf(float f) {
    unsigned int u = __float_as_uint(f);
    u += 0x7fffu + ((u >> 16) & 1u);
    return (unsigned short)(u >> 16);
}
__device__ __forceinline__ float bf2f(unsigned short s) {
    return __uint_as_float(((unsigned int)s) << 16);
}
__device__ __forceinline__ float sigmoidf_(float x) { return 1.0f / (1.0f + __expf(-x)); }
__device__ __forceinline__ float tanhf_(float x)    { return 1.0f - 2.0f / (1.0f + __expf(2.0f * x)); }

// 4 pipelined L1-bypass / XCD-L2-HIT loads: sc0 only (r17, verified).
__device__ __forceinline__ void load4_sc0(const unsigned short* p,
                                          bf16x8& r0, bf16x8& r1,
                                          bf16x8& r2, bf16x8& r3) {
    asm volatile(
        "global_load_dwordx4 %0, %4, off sc0\n\t"
        "global_load_dwordx4 %1, %4, off offset:64 sc0\n\t"
        "global_load_dwordx4 %2, %4, off offset:128 sc0\n\t"
        "global_load_dwordx4 %3, %4, off offset:192 sc0\n\t"
        "s_waitcnt vmcnt(0)"
        : "=&v"(r0), "=&v"(r1), "=&v"(r2), "=&v"(r3)
        : "v"(p)
        : "memory");
}

#define N_WHH  (3 * KP * KP)
#define N_WGM  (2 * KP * KP)
#define N_GI   (3 * NVT * KP)
#define N_IDW  (2 * NN * KP)
#define N_WRT  (KP * NN)
#define N_MSGB (BATCH * KP)
#define N_ADJC (BATCH * NN)
#define N_TOT  (N_WHH + N_WGM + N_GI + N_IDW + N_WRT + N_MSGB + N_ADJC)

// cb layout (u32): [0..7] claim counters; [16 .. 16+8*512) arrival flags
// (per XCD: 32 slots x 16-u32 stride).
#define CB_WORDS (16 + 8 * 512 + 8 * 16)

__global__ void prep_kernel(const float* __restrict__ W_hh, const float* __restrict__ Wg,
                            const float* __restrict__ Wm, const float* __restrict__ W_ih,
                            const float* __restrict__ b_ih, const float* __restrict__ b_hh,
                            const float* __restrict__ bg, const float* __restrict__ W_reg,
                            const float* __restrict__ adj,
                            unsigned short* __restrict__ Whh_p, unsigned short* __restrict__ Wgm_p,
                            float* __restrict__ gi_tab, float* __restrict__ idw,
                            float* __restrict__ WregT, unsigned short* __restrict__ MsgB,
                            unsigned int* __restrict__ adjcG)
{
    for (int i = blockIdx.x * blockDim.x + threadIdx.x; i < N_TOT; i += gridDim.x * blockDim.x) {
        int j = i;
        if (j < N_WHH) {
            int g = j >> 18, rem = j & (KP * KP - 1);
            int h = rem >> 9, k = rem & (KP - 1);
            float val = 0.0f;
            if (h < HS) {
                if (k < HS)        val = W_hh[(size_t)(g * HS + h) * HS + k];
                else if (k == HS)  val = b_hh[g * HS + h];   // bias folded at k=501
            }
            Whh_p[j] = f2bf(val);
            continue;
        }
        j -= N_WHH;
        if (j < N_WGM) {
            int m = j >> 18, rem = j & (KP * KP - 1);
            int h = rem >> 9, k = rem & (KP - 1);
            const float* src = m ? Wm : Wg;
            Wgm_p[j] = (h < HS && k < HS) ? f2bf(src[(size_t)h * VS + k]) : (unsigned short)0;
            continue;
        }
        j -= N_WGM;
        if (j < N_GI) {
            int g = j >> 14, typ = (j >> 9) & 31, h = j & (KP - 1);
            gi_tab[j] = (h < HS) ? (W_ih[(size_t)(g * HS + h) * NVT + typ] + b_ih[g * HS + h]) : 0.0f;
            continue;
        }
        j -= N_GI;
        if (j < N_IDW) {
            int m = j >> 14, v = (j >> 9) & 31, h = j & (KP - 1);
            float val = 0.0f;
            if (h < HS)
                val = m ? Wm[(size_t)h * VS + HS + v]
                        : (Wg[(size_t)h * VS + HS + v] + bg[h]);
            idw[j] = val;
            continue;
        }
        j -= N_IDW;
        if (j < N_WRT) {
            int k = j >> 5, ii = j & 31;
            WregT[j] = (k < HS) ? W_reg[(size_t)ii * HS + k] : 0.0f;
            continue;
        }
        j -= N_WRT;
        if (j < N_MSGB) {
            int k = j & (KP - 1);
            MsgB[j] = (k == HS) ? (unsigned short)0x3F80 : (unsigned short)0;  // bias col = 1.0
            continue;
        }
        j -= N_MSGB;
        {
            int b = j >> 5, vp = j & 31;
            unsigned int bits = 0;
            #pragma unroll
            for (int u = 0; u < 32; u++)
                bits |= (adj[((size_t)b * NN + u) * NN + vp] != 0.0f ? 1u : 0u) << u;
            adjcG[j] = bits;
        }
    }
}

// All-poll slice barrier (32 blocks, one XCD): arrival = own-slot store;
// EVERY block wave-polls all 32 flags directly (no master/release relay).
// 2 fabric hops instead of 4.
__device__ __forceinline__ void sbar(unsigned int* flags, int slot, unsigned int ph) {
    __syncthreads();
    const int t = threadIdx.x;
    if (t < 64) {
        if (t == 0)
            __hip_atomic_store(&flags[slot * 16], ph, __ATOMIC_RELAXED,
                               __HIP_MEMORY_SCOPE_AGENT);
        unsigned long long notready;
        do {
            const unsigned int fv = (t < 32)
                ? __hip_atomic_load(&flags[t * 16], __ATOMIC_RELAXED,
                                    __HIP_MEMORY_SCOPE_AGENT)
                : ph;
            notready = __ballot(fv < ph);
            if (notready) __builtin_amdgcn_s_sleep(1);
        } while (notready);
    }
    __syncthreads();
}

// Persistent, XCD-local. 1024 threads (16 waves = 4/SIMD), split-K4.
// WLDS fragment-major (conflict-free weight reads, r14).
__global__ __launch_bounds__(1024, 4) void dvae_kernel(
    const unsigned short* __restrict__ Whh,   // [3*512][512] bf16 (k=501 = b_hh)
    const unsigned short* __restrict__ Wgm,   // [2*512][512] bf16
    const float* __restrict__ gi_tab,         // [3][32][512]
    const float* __restrict__ idw,            // [2][32][512]
    const int*   __restrict__ types,          // [512][32]
    const unsigned int* __restrict__ adjcG,   // [512][32] bitmask over u
    unsigned short* __restrict__ MsgB,        // [512][512] bf16 (+bias col 501)
    unsigned short* __restrict__ HvB,         // [512][512] bf16
    unsigned short* __restrict__ Ghist,       // [256 role][32 u][64 b][16 h] bf16
    float* __restrict__ HvF,                  // [512][512] f32 (final step)
    unsigned int* __restrict__ cb)            // claim + flags
{
    __shared__ unsigned short WLDS[5 * 8192];     // 80 KB fragment-major weights
    __shared__ float          Cred[3 * 12 * 256]; // 36 KB split-K reduce (kh=1..3)
    __shared__ float          MsgF_L[64 * 16];    // 4 KB f32 Msg mirror (own patch)
    __shared__ unsigned short GvL[64 * 16];       // 2 KB G_v staging
    __shared__ unsigned int   adjcL[64 * 32];     // 8 KB
    __shared__ int            slotS;

    // ---- self-assignment: slice == XCD ----
    int xcd;
    asm volatile("s_getreg_b32 %0, hwreg(HW_REG_XCC_ID)" : "=s"(xcd));
    xcd &= 7;
    if (threadIdx.x == 0)
        slotS = (int)__hip_atomic_fetch_add(&cb[xcd], 1u, __ATOMIC_RELAXED,
                                            __HIP_MEMORY_SCOPE_AGENT);
    __syncthreads();
    const int slot = slotS;
    if (slot >= 32) return;                      // surplus block
    const int hblk = slot, bslc = xcd;
    unsigned int* flags = cb + 16 + (bslc << 9);

    const int t    = threadIdx.x;
    const int lane = t & 63, w = t >> 6;          // 16 waves
    const int c16  = lane & 15, kg = lane >> 4;
    const int bt   = w & 3, kh = w >> 2;          // wave: batch-tile x K-quarter
    const int lofs = lane * 8;

    // ---- stage weights into LDS, fragment-major
    {
        const int kkf = t >> 6, l = t & 63;
        const int r16 = l & 15, k0 = (l >> 4) * 8 + kkf * 32;
        #pragma unroll
        for (int T = 0; T < 5; T++) {
            const unsigned short* src = (T < 3)
                ? Whh + (((size_t)(T * 512 + hblk * 16 + r16)) << 9) + k0
                : Wgm + (((size_t)((T - 3) * 512 + hblk * 16 + r16)) << 9) + k0;
            *(bf16x8*)&WLDS[T * 8192 + kkf * 512 + l * 8] = *(const bf16x8*)src;
        }
    }
    for (int i = t; i < 64 * 32; i += 1024) adjcL[i] = adjcG[bslc * (64 * 32) + i];
    for (int i = t; i < 64 * 16; i += 1024) MsgF_L[i] = 0.0f;
    __syncthreads();

    unsigned short* Gblk = Ghist + (size_t)(bslc * 32 + hblk) * (32 * 64 * 16);
    unsigned int ph = 0;

    for (int v = 0; v < NN; v++) {
        // ======== phase A: gh = Msg @ Whh^T (own 16 h, 64 rows, split-K4) ========
        f32x4 a0 = {0.f,0.f,0.f,0.f}, a1 = a0, a2 = a0;
        {
            const unsigned short* aptr =
                MsgB + (((size_t)(bslc * 64 + bt * 16 + c16)) << 9) + kh * 128 + kg * 8;
            bf16x8 af[4];
            load4_sc0(aptr, af[0], af[1], af[2], af[3]);
            #pragma unroll
            for (int kk = 0; kk < 4; kk++) {
                const int wo = (kh * 4 + kk) * 512 + lofs;
                a0 = __builtin_amdgcn_mfma_f32_16x16x32_bf16(af[kk], *(const bf16x8*)&WLDS[0 * 8192 + wo], a0, 0, 0, 0);
                a1 = __builtin_amdgcn_mfma_f32_16x16x32_bf16(af[kk], *(const bf16x8*)&WLDS[1 * 8192 + wo], a1, 0, 0, 0);
                a2 = __builtin_amdgcn_mfma_f32_16x16x32_bf16(af[kk], *(const bf16x8*)&WLDS[2 * 8192 + wo], a2, 0, 0, 0);
            }
        }
        if (kh > 0) {
            #pragma unroll
            for (int j = 0; j < 4; j++) {
                const int pi = (kg * 4 + j) * 16 + c16;
                Cred[((kh - 1) * 12 + bt * 3 + 0) * 256 + pi] = a0[j];
                Cred[((kh - 1) * 12 + bt * 3 + 1) * 256 + pi] = a1[j];
                Cred[((kh - 1) * 12 + bt * 3 + 2) * 256 + pi] = a2[j];
            }
        }
        __syncthreads();
        if (kh == 0) {
            const int h = hblk * 16 + c16;
            const bool ok = (h < HS);
            #pragma unroll
            for (int j = 0; j < 4; j++) {
                const int pi = (kg * 4 + j) * 16 + c16;
                const float s0 = a0[j] + Cred[(0 * 12 + bt * 3 + 0) * 256 + pi]
                                       + Cred[(1 * 12 + bt * 3 + 0) * 256 + pi]
                                       + Cred[(2 * 12 + bt * 3 + 0) * 256 + pi];
                const float s1 = a1[j] + Cred[(0 * 12 + bt * 3 + 1) * 256 + pi]
                                       + Cred[(1 * 12 + bt * 3 + 1) * 256 + pi]
                                       + Cred[(2 * 12 + bt * 3 + 1) * 256 + pi];
                const float s2 = a2[j] + Cred[(0 * 12 + bt * 3 + 2) * 256 + pi]
                                       + Cred[(1 * 12 + bt * 3 + 2) * 256 + pi]
                                       + Cred[(2 * 12 + bt * 3 + 2) * 256 + pi];
                const int bl = bt * 16 + kg * 4 + j;
                const int bg_ = bslc * 64 + bl;
                float hv = 0.0f;
                if (ok) {
                    const int typ = types[bg_ * 32 + v];
                    const float gr = gi_tab[(0 * 32 + typ) * 512 + h];
                    const float gz = gi_tab[(1 * 32 + typ) * 512 + h];
                    const float gn = gi_tab[(2 * 32 + typ) * 512 + h];
                    const float hmsg = MsgF_L[bl * 16 + c16];
                    const float r = sigmoidf_(gr + s0);
                    const float z = sigmoidf_(gz + s1);
                    const float n = tanhf_(gn + r * s2);
                    hv = (1.0f - z) * n + z * hmsg;
                }
                HvB[((size_t)bg_ << 9) + h] = f2bf(hv);
                if (v == NN - 1) HvF[((size_t)bg_ << 9) + h] = hv;
            }
        }
        if (v == NN - 1) break;
        sbar(flags, hblk, ++ph);

        // ======== phase B: z = Hv @ {Wg,Wm}^T ========
        f32x4 b0 = {0.f,0.f,0.f,0.f}, b1 = b0;
        {
            const unsigned short* aptr =
                HvB + (((size_t)(bslc * 64 + bt * 16 + c16)) << 9) + kh * 128 + kg * 8;
            bf16x8 bfr[4];
            load4_sc0(aptr, bfr[0], bfr[1], bfr[2], bfr[3]);
            #pragma unroll
            for (int kk = 0; kk < 4; kk++) {
                const int wo = (kh * 4 + kk) * 512 + lofs;
                b0 = __builtin_amdgcn_mfma_f32_16x16x32_bf16(bfr[kk], *(const bf16x8*)&WLDS[3 * 8192 + wo], b0, 0, 0, 0);
                b1 = __builtin_amdgcn_mfma_f32_16x16x32_bf16(bfr[kk], *(const bf16x8*)&WLDS[4 * 8192 + wo], b1, 0, 0, 0);
            }
        }
        if (kh > 0) {
            #pragma unroll
            for (int j = 0; j < 4; j++) {
                const int pi = (kg * 4 + j) * 16 + c16;
                Cred[((kh - 1) * 12 + bt * 3 + 0) * 256 + pi] = b0[j];
                Cred[((kh - 1) * 12 + bt * 3 + 1) * 256 + pi] = b1[j];
            }
        }
        __syncthreads();
        if (kh == 0) {
            const int h = hblk * 16 + c16;
            const bool ok = (h < HS);
            #pragma unroll
            for (int j = 0; j < 4; j++) {
                const int pi = (kg * 4 + j) * 16 + c16;
                const float s0 = b0[j] + Cred[(0 * 12 + bt * 3 + 0) * 256 + pi]
                                       + Cred[(1 * 12 + bt * 3 + 0) * 256 + pi]
                                       + Cred[(2 * 12 + bt * 3 + 0) * 256 + pi];
                const float s1 = b1[j] + Cred[(0 * 12 + bt * 3 + 1) * 256 + pi]
                                       + Cred[(1 * 12 + bt * 3 + 1) * 256 + pi]
                                       + Cred[(2 * 12 + bt * 3 + 1) * 256 + pi];
                const int bl = bt * 16 + kg * 4 + j;
                float gq = 0.0f;
                if (ok) {
                    const float zg = s0 + idw[(0 * 32 + v) * 512 + h];
                    const float zm = s1 + idw[(1 * 32 + v) * 512 + h];
                    gq = sigmoidf_(zg) * zm;
                }
                GvL[bl * 16 + c16] = f2bf(gq);
            }
        }
        __syncthreads();
        // ---- gather: persist G_v (block-private), assemble Msg_{v+1} own patch
        if (t < 128) {
            const int bl = t >> 1, h8 = (t & 1) * 8;
            const bf16x8 g = *(const bf16x8*)&GvL[bl * 16 + h8];
            *(bf16x8*)&Gblk[((size_t)v * 64 + bl) * 16 + h8] = g;

            float msg[8] = {0.f,0.f,0.f,0.f,0.f,0.f,0.f,0.f};
            unsigned int mask = adjcL[bl * 32 + (v + 1)] & ((2u << v) - 1u);   // u <= v
            if ((mask >> v) & 1u) {
                #pragma unroll
                for (int x = 0; x < 8; x++) msg[x] += bf2f((unsigned short)g[x]);
                mask &= ~(1u << v);
            }
            while (mask) {
                const int u = __builtin_ctz(mask); mask &= mask - 1u;
                const bf16x8 a = *(const bf16x8*)&Gblk[((size_t)u * 64 + bl) * 16 + h8];
                #pragma unroll
                for (int x = 0; x < 8; x++) msg[x] += bf2f((unsigned short)a[x]);
            }
            const int hb_ = hblk * 16 + h8;
            if (hb_ <= HS && HS < hb_ + 8) msg[HS - hb_] = 1.0f;   // bias col k=501
            bf16x8 mb;
            #pragma unroll
            for (int x = 0; x < 8; x++) mb[x] = (short)f2bf(msg[x]);
            *(bf16x8*)&MsgB[(((size_t)(bslc * 64 + bl)) << 9) + hb_] = mb;
            #pragma unroll
            for (int x = 0; x < 8; x++) MsgF_L[bl * 16 + h8 + x] = msg[x];
        }
        sbar(flags, hblk, ++ph);
    }
}

// mu = Hv31 @ W_reg^T + b_reg
__global__ __launch_bounds__(256) void final_kernel(
    const float* __restrict__ HvF,       // [512][512]
    const float* __restrict__ WregT,     // [512][32]
    const float* __restrict__ b_reg,     // [32]
    float* __restrict__ out)             // [512][32]
{
    const int t = blockIdx.x * 256 + threadIdx.x;
    const int b = t >> 5, i = t & 31;
    float s = b_reg[i];
    const float* hp = HvF + ((size_t)b << 9);
    #pragma unroll 4
    for (int k = 0; k < KP; k++) s += hp[k] * WregT[k * 32 + i];
    out[b * 32 + i] = s;
}

extern "C" void kernel_launch(void* const* d_in, const int* in_sizes, int n_in,
                              void* d_out, int out_size, void* d_ws, size_t ws_size,
                              hipStream_t stream) {
    const int*   node_types = (const int*)  d_in[0];
    const float* adj        = (const float*)d_in[1];
    const float* Wg         = (const float*)d_in[2];
    const float* bg         = (const float*)d_in[3];
    const float* Wm         = (const float*)d_in[4];
    const float* W_ih       = (const float*)d_in[5];
    const float* b_ih       = (const float*)d_in[6];
    const float* W_hh       = (const float*)d_in[7];
    const float* b_hh       = (const float*)d_in[8];
    const float* W_reg      = (const float*)d_in[9];
    const float* b_reg      = (const float*)d_in[10];
    float* out = (float*)d_out;

    char* p = (char*)d_ws;
    unsigned short* Whh_p = (unsigned short*)p; p += (size_t)N_WHH * 2;
    unsigned short* Wgm_p = (unsigned short*)p; p += (size_t)N_WGM * 2;
    float* gi_tab = (float*)p; p += (size_t)N_GI * 4;
    float* idw    = (float*)p; p += (size_t)N_IDW * 4;
    float* WregT  = (float*)p; p += (size_t)N_WRT * 4;
    float* HvF    = (float*)p; p += (size_t)BATCH * KP * 4;
    unsigned short* MsgB = (unsigned short*)p; p += (size_t)N_MSGB * 2;
    unsigned short* HvB  = (unsigned short*)p; p += (size_t)BATCH * KP * 2;
    unsigned int* adjcG  = (unsigned int*)p;  p += (size_t)N_ADJC * 4;
    unsigned int* cb     = (unsigned int*)p;  p += (size_t)CB_WORDS * 4;
    unsigned short* Ghist = (unsigned short*)p; p += (size_t)256 * 32 * 64 * 16 * 2;

    hipMemsetAsync(cb, 0, CB_WORDS * 4, stream);
    prep_kernel<<<1024, 256, 0, stream>>>(W_hh, Wg, Wm, W_ih, b_ih, b_hh, bg, W_reg, adj,
                                          Whh_p, Wgm_p, gi_tab, idw, WregT, MsgB, adjcG);
    dvae_kernel<<<1024, 1024, 0, stream>>>(Whh_p, Wgm_p, gi_tab, idw, node_types, adjcG,
                                           MsgB, HvB, Ghist, HvF, cb);
    final_kernel<<<(BATCH * NN) / 256, 256, 0, stream>>>(HvF, WregT, b_reg, out);
}